// Round 1
// baseline (112.784 us; speedup 1.0000x reference)
//
#include <hip/hip_runtime.h>

// GPDGaussian: per-pixel 629x3 conv -> (m, S=R^T diag(s) R, s)
// One wave (64 threads) per pixel; R rows in registers (lanes 0..33),
// 561 Givens rotations fully unrolled (compile-time register indices).

#define CCH 34          // s/m channels
#define ACH 561         // rotation angles = 34*33/2
#define HWPIX 4096      // 64*64
#define NPIX 16384      // 4*64*64

// output offsets (floats)
#define OFF_S 557056        // 16384*34
#define OFF_s 19496960      // 557056 + 16384*1156

__global__ __launch_bounds__(64) void gpd_kernel(
    const float* __restrict__ x,     // (4,3,64,64)
    const float* __restrict__ Wm,    // (629,3)
    const float* __restrict__ bvec,  // (629,)
    float* __restrict__ out)
{
    // phase-1 region (cos/sin + sqrt(s)) overlaid by phase-3 S staging
    __shared__ alignas(16) char smem_u[4624];
    float2* lds_cs  = (float2*)smem_u;           // [561] (cos,sin)
    float*  lds_rsp = (float*)(smem_u + 4488);   // [34]  sqrt(s)
    float*  lds_S   = (float*)smem_u;            // [1156] phase C staging
    __shared__ alignas(16) float lds_V[CCH * 36]; // V rows padded to 36 floats

    const int p    = blockIdx.x;
    const int lane = threadIdx.x;
    const int b    = p >> 12;        // batch
    const int hw   = p & 4095;       // h*64+w

    // wave-uniform pixel inputs (broadcast loads)
    const float x0 = x[(b * 3 + 0) * HWPIX + hw];
    const float x1 = x[(b * 3 + 1) * HWPIX + hw];
    const float x2 = x[(b * 3 + 2) * HWPIX + hw];

    float* out_m = out + (size_t)p * CCH;
    float* out_S = out + OFF_S + (size_t)p * (CCH * CCH);
    float* out_s = out + OFF_s + (size_t)(b * CCH) * HWPIX + hw;

    const float LOG2E = 1.4426950408889634f;

    // ---- Phase A: 629-channel 1x1 conv + activations (all 64 lanes) ----
    for (int o = lane; o < 2 * CCH + ACH; o += 64) {
        float wv = fmaf(Wm[o * 3 + 0], x0,
                   fmaf(Wm[o * 3 + 1], x1, Wm[o * 3 + 2] * x2)) + bvec[o];
        if (o < CCH) {
            out_m[o] = wv;                                  // mean, (p,34) layout
        } else if (o < 2 * CCH) {
            // s = SMIN + (SMAX-SMIN)*sigmoid(wv)
            float e  = __builtin_amdgcn_exp2f(-wv * LOG2E);
            float sg = __builtin_amdgcn_rcpf(1.0f + e);
            float sv = fmaf(999.999f, sg, 0.001f);
            int c = o - CCH;
            out_s[(size_t)c * HWPIX] = sv;                  // (b,c,h,w) layout
            lds_rsp[c] = __builtin_amdgcn_sqrtf(sv);
        } else {
            // t = tanh(wv); angle = pi*t; cos/sin via HW (input in revolutions)
            float e = __builtin_amdgcn_exp2f((2.0f * LOG2E) * wv);
            float t = 1.0f - 2.0f * __builtin_amdgcn_rcpf(e + 1.0f);
            float rev = 0.5f * t;                           // (pi*t)/(2*pi)
            lds_cs[o - 2 * CCH] = make_float2(__builtin_amdgcn_cosf(rev),
                                              __builtin_amdgcn_sinf(rev));
        }
    }
    __syncthreads();

    // ---- Phase B: 561 Givens rotations; lane m owns row m of R in VGPRs ----
    if (lane < CCH) {
        float R[CCH];
        #pragma unroll
        for (int k = 0; k < CCH; ++k) R[k] = (k == lane) ? 1.0f : 0.0f;

        int pidx = 0;
        #pragma unroll
        for (int i = 0; i < CCH - 1; ++i) {
            #pragma unroll
            for (int j = i + 1; j < CCH; ++j) {
                float2 cs = lds_cs[pidx];        // wave-uniform broadcast read
                float ri = R[i], rj = R[j];
                R[i] = fmaf(cs.x, ri,  cs.y * rj);
                R[j] = fmaf(cs.x, rj, -cs.y * ri);
                ++pidx;
            }
        }

        // V = diag(sqrt(s)) * R  ->  LDS (rows padded to 36 for 16B alignment)
        float rs = lds_rsp[lane];
        #pragma unroll
        for (int n = 0; n < CCH; ++n) lds_V[lane * 36 + n] = rs * R[n];
    }
    __syncthreads();

    // ---- Phase C: S = V^T V ; lane k computes S row k ----
    if (lane < CCH) {
        float acc[CCH];
        #pragma unroll
        for (int n = 0; n < CCH; ++n) acc[n] = 0.0f;
        for (int m = 0; m < CCH; ++m) {          // rolled: LDS addrs runtime-ok
            float vk = lds_V[m * 36 + lane];     // column k element (no conflict)
            #pragma unroll
            for (int n = 0; n < CCH; ++n)
                acc[n] = fmaf(vk, lds_V[m * 36 + n], acc[n]);  // row broadcast
        }
        #pragma unroll
        for (int n = 0; n < CCH; ++n) lds_S[lane * CCH + n] = acc[n];
    }
    __syncthreads();

    // ---- coalesced float4 write of S (1156 floats = 289 float4) ----
    {
        const float4* s4 = (const float4*)lds_S;
        float4* o4 = (float4*)out_S;
        for (int e = lane; e < (CCH * CCH) / 4; e += 64)
            o4[e] = s4[e];
    }
}

extern "C" void kernel_launch(void* const* d_in, const int* in_sizes, int n_in,
                              void* d_out, int out_size, void* d_ws, size_t ws_size,
                              hipStream_t stream) {
    const float* x  = (const float*)d_in[0];
    const float* W  = (const float*)d_in[1];
    const float* bv = (const float*)d_in[2];
    float* out = (float*)d_out;
    hipLaunchKernelGGL(gpd_kernel, dim3(NPIX), dim3(64), 0, stream,
                       x, W, bv, out);
}